// Round 8
// baseline (333.458 us; speedup 1.0000x reference)
//
#include <hip/hip_runtime.h>
#include <stdint.h>

// Problem constants (fixed by the reference): B=2, S=2048, D=2048, Dh=64, Hq=32, Hkv=8, G=4.
#define S_LEN   2048
#define D_MODEL 2048
#define DKV     512

typedef __attribute__((ext_vector_type(8))) short short8;   // 8 x bf16
typedef __attribute__((ext_vector_type(4))) float f32x4;

__device__ static inline unsigned short f2bf(float f) {     // RNE float->bf16 (finite values)
  unsigned u = __builtin_bit_cast(unsigned, f);
  u += 0x7FFFu + ((u >> 16) & 1u);
  return (unsigned short)(u >> 16);
}
__device__ static inline float bf2f(unsigned short h) {
  return __builtin_bit_cast(float, ((unsigned)h) << 16);
}
// pack hi16(f0), hi16(f1) -> one dword (bf16 truncation; 1 v_perm_b32)
__device__ static inline unsigned packtrunc2(float f0, float f1) {
  return __builtin_amdgcn_perm(__builtin_bit_cast(unsigned, f1),
                               __builtin_bit_cast(unsigned, f0), 0x07060302u);
}

__device__ static inline void gload_lds16(const void* g, void* lds) {
  __builtin_amdgcn_global_load_lds((const __attribute__((address_space(1))) void*)g,
                                   (__attribute__((address_space(3))) void*)lds,
                                   16, 0, 0);
}

template <int N>
__device__ __forceinline__ void wait_vm() {
  if constexpr (N == 8)      asm volatile("s_waitcnt vmcnt(8)" ::: "memory");
  else if constexpr (N == 6) asm volatile("s_waitcnt vmcnt(6)" ::: "memory");
  else if constexpr (N == 4) asm volatile("s_waitcnt vmcnt(4)" ::: "memory");
  else if constexpr (N == 3) asm volatile("s_waitcnt vmcnt(3)" ::: "memory");
  else                       asm volatile("s_waitcnt vmcnt(0)" ::: "memory");
}

// fp32 -> bf16 bulk conversion for all 5 inputs in ONE launch (exact region split, units of 8 floats).
__global__ __launch_bounds__(256) void cvt_all_kernel(
    const float* __restrict__ x, const float* __restrict__ wq, const float* __restrict__ wk,
    const float* __restrict__ wv, const float* __restrict__ wo,
    unsigned short* __restrict__ xb, unsigned short* __restrict__ wqb,
    unsigned short* __restrict__ wkb, unsigned short* __restrict__ wvb,
    unsigned short* __restrict__ wob) {
  int i = blockIdx.x * 256 + threadIdx.x;          // 0 .. 2359296-1
  const float* s; unsigned short* d;
  if (i < 1048576)      { s = x;  d = xb;  }
  else if (i < 1572864) { s = wq; d = wqb; i -= 1048576; }
  else if (i < 1703936) { s = wk; d = wkb; i -= 1572864; }
  else if (i < 1835008) { s = wv; d = wvb; i -= 1703936; }
  else                  { s = wo; d = wob; i -= 1835008; }
  const float4 a = ((const float4*)s)[i * 2];
  const float4 b = ((const float4*)s)[i * 2 + 1];
  unsigned short u[8] = {f2bf(a.x), f2bf(a.y), f2bf(a.z), f2bf(a.w),
                         f2bf(b.x), f2bf(b.y), f2bf(b.z), f2bf(b.w)};
  *(uint4*)(d + (size_t)i * 8) = *(const uint4*)u;
}

// ---------------------------------------------------------------------------------------------
// Deep-pipelined GEMM: C(M,N) = A(M,K=2048) @ B(N,K)^T, bf16 inputs.  (R1 structure)
// RMODE 0: plain. RMODE 1: fused RoPE on the fp32 accumulator before the bf16 store (K).
// RMODE 2: fused RoPE + 0.1803 log2-softmax Q scale.
//   RoPE pair (col, col^1) lives in lanes (lcol, lcol^1) of the same row -> __shfl_xor(v,1).
//   theta = (row & 2047) * 10000^(-(col&63)/64 rounded to pair) ; identical math to the old
//   rope_both_kernel but applied in fp32 (one fewer bf16 quantization).
// ---------------------------------------------------------------------------------------------
template <int BM, int CMODE, int RMODE, typename CT>
__device__ __forceinline__ void gemm_deep_body(
    const unsigned short* __restrict__ A, int lda,
    const unsigned short* __restrict__ B, int ldb,
    CT* __restrict__ C, int ldc, int m0, int n0, unsigned short* ldsu) {
  constexpr int MI = BM / 32;             // 8 (BM=256) or 4 (BM=128)
  constexpr int NI = 4;
  constexpr int A_BYTES = BM * 64;        // BM*32*2B : 16KB or 8KB
  constexpr int B_BYTES = 256 * 64;       // 16KB
  constexpr int TILE_BYTES = A_BYTES + B_BYTES;
  constexpr int AL = BM / 128;            // A stage-loads per thread per phase: 2 or 1
  constexpr int LOADS = AL + 2;           // total stage-loads/thread/phase: 4 or 3
  constexpr int VMS = 2 * LOADS;          // steady-state vmcnt (retire 3-phases-old tile)

  const int tid  = threadIdx.x;
  const int lane = tid & 63;
  const int w    = tid >> 6;              // 0..7
  const int wm   = w >> 2;                // 0..1  (M halves)
  const int wn   = w & 3;                 // 0..3  (N quarters)
  const int lcol = lane & 15;
  const int lq   = lane >> 4;
  char* const ldsb = (char*)ldsu;

  // ---- staging lane constants (inverse swizzle on the global side) ----
  const int sl   = (lane & 7) ^ (lane >> 3);   // logical slab this lane must fetch
  const int colg = (sl & 3) * 8;               // element col within the 32-wide K-tile
  const unsigned short* gA[AL];
  const unsigned short* gB[2];
#pragma unroll
  for (int L = 0; L < AL; ++L) {
    const int r = 2 * (L * 64 + w * 8 + (lane >> 3)) + (sl >> 2);
    gA[L] = A + (size_t)(m0 + r) * lda + colg;
  }
#pragma unroll
  for (int L = 0; L < 2; ++L) {
    const int r = 2 * (L * 64 + w * 8 + (lane >> 3)) + (sl >> 2);
    gB[L] = B + (size_t)(n0 + r) * ldb + colg;
  }

  auto stage = [&](int tt) {
    char* const sb = ldsb + (tt & 3) * TILE_BYTES;
#pragma unroll
    for (int L = 0; L < AL; ++L)
      gload_lds16(gA[L] + tt * 32, sb + L * 8192 + w * 1024);
#pragma unroll
    for (int L = 0; L < 2; ++L)
      gload_lds16(gB[L] + tt * 32, sb + A_BYTES + L * 8192 + w * 1024);
  };

  // ---- fragment-read lane constant (swizzled) ----
  const int sR    = (((lcol & 1) << 2) | lq) ^ ((lcol >> 1) & 7);
  const int rdoff = (lcol >> 1) * 128 + sR * 16;

  f32x4 acc[MI][NI] = {};

  auto compute_tile = [&](char* buf) {
    short8 af[MI], bfr[NI];
#pragma unroll
    for (int mi = 0; mi < MI; ++mi)
      af[mi] = *(const short8*)(buf + wm * (MI * 1024) + mi * 1024 + rdoff);
#pragma unroll
    for (int ni = 0; ni < NI; ++ni)
      bfr[ni] = *(const short8*)(buf + A_BYTES + wn * 4096 + ni * 1024 + rdoff);
    __builtin_amdgcn_s_setprio(1);
#pragma unroll
    for (int mi = 0; mi < MI; ++mi)
#pragma unroll
      for (int ni = 0; ni < NI; ++ni)
        acc[mi][ni] = __builtin_amdgcn_mfma_f32_16x16x32_bf16(af[mi], bfr[ni], acc[mi][ni], 0, 0, 0);
    __builtin_amdgcn_s_setprio(0);
  };

  // prologue: 3 tiles in flight
  stage(0); stage(1); stage(2);

#define GPHASE(T, VMW, DOSTG)                          \
  do {                                                 \
    wait_vm<VMW>();                                    \
    __builtin_amdgcn_s_barrier();                      \
    asm volatile("" ::: "memory");                     \
    __builtin_amdgcn_sched_barrier(0);                 \
    if (DOSTG) stage((T) + 3);                         \
    compute_tile(ldsb + ((T) & 3) * TILE_BYTES);       \
  } while (0)

  for (int t4 = 0; t4 < 15; ++t4) {
    const int t = t4 * 4;
    GPHASE(t + 0, VMS, true);
    GPHASE(t + 1, VMS, true);
    GPHASE(t + 2, VMS, true);
    GPHASE(t + 3, VMS, true);
  }
  GPHASE(60, VMS,   true);
  GPHASE(61, VMS,   false);
  GPHASE(62, LOADS, false);
  GPHASE(63, 0,     false);
#undef GPHASE

  // epilogue (m97-verified C/D mapping; optional fused RoPE)
#pragma unroll
  for (int mi = 0; mi < MI; ++mi)
#pragma unroll
    for (int ni = 0; ni < NI; ++ni)
#pragma unroll
      for (int r = 0; r < 4; ++r) {
        const int row = m0 + wm * (MI * 16) + mi * 16 + lq * 4 + r;
        const int col = n0 + wn * 64 + ni * 16 + lcol;
        float v = acc[mi][ni][r];
        if constexpr (RMODE > 0) {
          const float p = __shfl_xor(v, 1);           // partner element of the (even,odd) pair
          const int d = col & 63;
          const float inv = exp2f(-0.41524101186091903f * (float)(d >> 1)); // 10000^(-2i/64)
          const float th  = (float)(row & (S_LEN - 1)) * inv;
          const float c = cosf(th), sn = sinf(th);
          v = (d & 1) ? (p * sn + v * c) : (v * c - p * sn);
          if constexpr (RMODE == 2) v *= 0.1803368801111244f;  // 1/sqrt(64)*log2(e)
        }
        if constexpr (CMODE == 1) {
          // V pre-transpose: row = b*2048+s, col = d(0..511) -> Vt[(b*512+d)*2048 + s]
          C[((size_t)((row >> 11) * 512 + col)) * 2048 + (row & 2047)] = f2bf(v);
        } else if constexpr (CMODE == 2) {
          C[(size_t)row * ldc + col] = v;
        } else {
          C[(size_t)row * ldc + col] = f2bf(v);
        }
      }
}

// Fused QKV projection + RoPE: 192 blocks (16 M-tiles x [8 Q + 2 K + 2 V]), 512 thr, 128KB LDS.
__global__ __launch_bounds__(512, 2) void qkv_gemm_kernel(
    const unsigned short* __restrict__ x,
    const unsigned short* __restrict__ Wq, const unsigned short* __restrict__ Wk,
    const unsigned short* __restrict__ Wv,
    unsigned short* __restrict__ Qo, unsigned short* __restrict__ Ko,
    unsigned short* __restrict__ Vt) {
  extern __shared__ __align__(16) unsigned short lds[];
  const int bid = blockIdx.x;                   // 192 = 8 XCDs * 24
  const int swz = (bid & 7) * 24 + (bid >> 3);  // bijective XCD swizzle (192 % 8 == 0)
  const int mt = swz / 12, nt = swz % 12;
  const int m0 = mt * 256;
  if (nt < 8)
    gemm_deep_body<256, 0, 2, unsigned short>(x, D_MODEL, Wq, D_MODEL, Qo, D_MODEL, m0, nt * 256, lds);
  else if (nt < 10)
    gemm_deep_body<256, 0, 1, unsigned short>(x, D_MODEL, Wk, D_MODEL, Ko, DKV, m0, (nt - 8) * 256, lds);
  else
    gemm_deep_body<256, 1, 0, unsigned short>(x, D_MODEL, Wv, D_MODEL, Vt, DKV, m0, (nt - 10) * 256, lds);
}

// O-projection: bf16 A (attn out) x bf16 Wo -> fp32 out. 256 blocks (32 x 8) = exact CU fill.
__global__ __launch_bounds__(512, 2) void oproj_gemm_kernel(
    const unsigned short* __restrict__ A, const unsigned short* __restrict__ Wo,
    float* __restrict__ C) {
  extern __shared__ __align__(16) unsigned short lds[];
  const int bid = blockIdx.x;                   // 256 = 8 XCDs * 32
  const int swz = (bid & 7) * 32 + (bid >> 3);
  const int mt = swz >> 3, nt = swz & 7;
  gemm_deep_body<128, 2, 0, float>(A, D_MODEL, Wo, D_MODEL, C, D_MODEL, mt * 128, nt * 256, lds);
}

// ---------------------------------------------------------------------------------------------
// Flash attention — EXACT session-best kernel (R0 original, 77.9 us measured):
// transposed scores (S^T = K@Q^T), non-rescaled log2-domain softmax, FOUR q-tiles per block
// {X,15-X,16+X,31-X} sharing every K/V LDS read (66 updates/block uniform, avg 2.32 tiles per
// kf/vf b128 read); P^T through LDS (Ps); l in VALU regs reduced by 2 shuffles.
// Grid (8, 32, 2); 2 blocks/CU (55KB LDS), 112 VGPR.
// Seven rounds of rewrites (R3-R7: in-register P, deferred PV, gload_lds deep pipe, 0-conflict
// swizzle) all landed at 82-87 us vs this kernel's 77.9 -> the 4-tile sharing + fewer
// iterations is the winning trade at the 2-waves/SIMD residency this compiler allows.
// ---------------------------------------------------------------------------------------------
__global__ __launch_bounds__(256, 2) void attn_kernel(const unsigned short* __restrict__ Q,
                                                      const unsigned short* __restrict__ K,
                                                      const unsigned short* __restrict__ Vt,
                                                      unsigned short* __restrict__ O) {
  const int hq = blockIdx.y;
  const int bb = blockIdx.z;
  const int hk = hq >> 2;
  const int tid  = threadIdx.x;
  const int lane = tid & 63;
  const int w    = tid >> 6;
  const int lcol = lane & 15;
  const int lq   = lane >> 4;
  const int trow = tid >> 2;            // staging row 0..63 (wave-private: w*16..w*16+15)
  const int tq   = (tid & 3) * 16;      // staging col quarter (16 elems = 32B)

  const int X = blockIdx.x;             // 0..7
  const int qt[4] = {X, 15 - X, 16 + X, 31 - X};   // ascending; total updates = 66

  // 72-elem rows (144B): 16B-aligned, non-pow2 bank stride. Ps[j] = Q tile j staging, then P^T.
  __shared__ unsigned short Ks[64 * 72];
  __shared__ unsigned short Vts[64 * 72];
  __shared__ unsigned short Ps[4][64 * 72];

  const int prow = w * 16 + lcol;

  // prefetch K/V tile 0 into registers
  uint4 kp0, kp1, vp0, vp1;
  {
    const unsigned short* gk = K + ((size_t)(bb * S_LEN + trow)) * DKV + hk * 64 + tq;
    kp0 = *(const uint4*)gk; kp1 = *(const uint4*)(gk + 8);
    const unsigned short* gv = Vt + ((size_t)(bb * DKV + hk * 64 + trow)) * S_LEN + tq;
    vp0 = *(const uint4*)gv; vp1 = *(const uint4*)(gv + 8);
  }

  // stage all 4 Q tiles (wave-private rows -> lgkm drain only, no barrier)
#pragma unroll
  for (int j = 0; j < 4; ++j) {
    const unsigned short* g = Q + ((size_t)(bb * S_LEN + qt[j] * 64 + trow)) * D_MODEL + hq * 64 + tq;
    *(uint4*)&Ps[j][trow * 72 + tq]     = *(const uint4*)g;
    *(uint4*)&Ps[j][trow * 72 + tq + 8] = *(const uint4*)(g + 8);
  }
  asm volatile("s_waitcnt lgkmcnt(0)" ::: "memory");

  short8 qf[4][2];                      // B-frags: n = q-row (w*16+lcol), k = d slab
#pragma unroll
  for (int j = 0; j < 4; ++j)
#pragma unroll
    for (int ks = 0; ks < 2; ++ks)
      qf[j][ks] = *(const short8*)&Ps[j][prow * 72 + ks * 32 + lq * 8];

  f32x4 Oacc[4][4] = {};                // [tile][dt]; O^T: col = q-row, row = d
  float lacc[4] = {0.f, 0.f, 0.f, 0.f}; // lq-partial row sums (reduced in epilogue)

  const int tmax = qt[3];
  for (int t = 0; t <= tmax; ++t) {
    __syncthreads();                    // all waves done reading Ks/Vts of iter t-1
    *(uint4*)&Ks[trow * 72 + tq]      = kp0;
    *(uint4*)&Ks[trow * 72 + tq + 8]  = kp1;
    *(uint4*)&Vts[trow * 72 + tq]     = vp0;
    *(uint4*)&Vts[trow * 72 + tq + 8] = vp1;
    if (t < tmax) {                     // prefetch next tile
      const int t1 = (t + 1) * 64;
      const unsigned short* gk = K + ((size_t)(bb * S_LEN + t1 + trow)) * DKV + hk * 64 + tq;
      kp0 = *(const uint4*)gk; kp1 = *(const uint4*)(gk + 8);
      const unsigned short* gv = Vt + ((size_t)(bb * DKV + hk * 64 + trow)) * S_LEN + t1 + tq;
      vp0 = *(const uint4*)gv; vp1 = *(const uint4*)(gv + 8);
    }
    __syncthreads();

    bool act[4];
#pragma unroll
    for (int j = 0; j < 4; ++j) act[j] = (t <= qt[j]);

    // ---- S phase: each kf b128 read feeds all active tiles' MFMAs ----
    f32x4 S[4][4] = {};                 // [tile][nt]
#pragma unroll
    for (int ks = 0; ks < 2; ++ks)
#pragma unroll
      for (int nt = 0; nt < 4; ++nt) {
        const short8 kf = *(const short8*)&Ks[(nt * 16 + lcol) * 72 + ks * 32 + lq * 8];
#pragma unroll
        for (int j = 0; j < 4; ++j)
          if (act[j])
            S[j][nt] = __builtin_amdgcn_mfma_f32_16x16x32_bf16(kf, qf[j][ks], S[j][nt], 0, 0, 0);
      }

    // ---- mask diagonal, p = exp2(S), accumulate l, pack P^T to LDS ----
#pragma unroll
    for (int j = 0; j < 4; ++j) {
      if (!act[j]) continue;
      if (t == qt[j]) {                 // diagonal tile for j
        const int qrow = qt[j] * 64 + prow;
#pragma unroll
        for (int nt = 0; nt < 4; ++nt)
#pragma unroll
          for (int r = 0; r < 4; ++r) {
            const int key = t * 64 + nt * 16 + lq * 4 + r;
            if (key > qrow) S[j][nt][r] = -1e30f;   // exp2 -> 0
          }
      }
#pragma unroll
      for (int nt = 0; nt < 4; ++nt) {
        const float p0 = __builtin_amdgcn_exp2f(S[j][nt][0]);
        const float p1 = __builtin_amdgcn_exp2f(S[j][nt][1]);
        const float p2 = __builtin_amdgcn_exp2f(S[j][nt][2]);
        const float p3 = __builtin_amdgcn_exp2f(S[j][nt][3]);
        lacc[j] += (p0 + p1) + (p2 + p3);
        unsigned u2[2] = {packtrunc2(p0, p1), packtrunc2(p2, p3)};
        *(uint2*)&Ps[j][prow * 72 + nt * 16 + lq * 4] = *(const uint2*)u2;
      }
    }
    asm volatile("s_waitcnt lgkmcnt(0)" ::: "memory");  // per-wave P write->read ordering

    // ---- O phase: each vf b128 read feeds all active tiles' MFMAs ----
#pragma unroll
    for (int ks = 0; ks < 2; ++ks) {
      short8 pf[4];
#pragma unroll
      for (int j = 0; j < 4; ++j)
        if (act[j]) pf[j] = *(const short8*)&Ps[j][prow * 72 + ks * 32 + lq * 8];
#pragma unroll
      for (int dt = 0; dt < 4; ++dt) {
        const short8 vf = *(const short8*)&Vts[(dt * 16 + lcol) * 72 + ks * 32 + lq * 8];
#pragma unroll
        for (int j = 0; j < 4; ++j)
          if (act[j])
            Oacc[j][dt] = __builtin_amdgcn_mfma_f32_16x16x32_bf16(vf, pf[j], Oacc[j][dt], 0, 0, 0);
      }
    }
  }

  // epilogue: reduce l across lq (2 shuffles per tile), normalize, store
#pragma unroll
  for (int j = 0; j < 4; ++j) {
    float l = lacc[j];
    l += __shfl_xor(l, 16);
    l += __shfl_xor(l, 32);
    const float inv = 1.0f / l;
    const int qrow = qt[j] * 64 + prow;
#pragma unroll
    for (int dt = 0; dt < 4; ++dt) {
      unsigned short u[4] = {f2bf(Oacc[j][dt][0] * inv), f2bf(Oacc[j][dt][1] * inv),
                             f2bf(Oacc[j][dt][2] * inv), f2bf(Oacc[j][dt][3] * inv)};
      *(uint2*)&O[(size_t)(bb * S_LEN + qrow) * D_MODEL + hq * 64 + dt * 16 + lq * 4] =
          *(const uint2*)u;
    }
  }
}

extern "C" void kernel_launch(void* const* d_in, const int* in_sizes, int n_in,
                              void* d_out, int out_size, void* d_ws, size_t ws_size,
                              hipStream_t stream) {
  const float* x  = (const float*)d_in[0];   // fp32 inputs per the reference dtypes
  const float* Wq = (const float*)d_in[1];
  const float* Wk = (const float*)d_in[2];
  const float* Wv = (const float*)d_in[3];
  const float* Wo = (const float*)d_in[4];
  float* out = (float*)d_out;                // fp32 output per the reference

  // Workspace (bf16 elements), total ~70 MiB:
  unsigned short* Qb  = (unsigned short*)d_ws;                 // 4096 x 2048
  unsigned short* Kb  = Qb  + (size_t)4096 * 2048;             // 4096 x 512
  unsigned short* Vtg = Kb  + (size_t)4096 * 512;              // 1024 x 2048 (V pre-transposed)
  unsigned short* Ab  = Vtg + (size_t)1024 * 2048;             // 4096 x 2048
  unsigned short* xb  = Ab  + (size_t)4096 * 2048;             // 4096 x 2048
  unsigned short* Wqb = xb  + (size_t)4096 * 2048;             // 2048 x 2048
  unsigned short* Wkb = Wqb + (size_t)2048 * 2048;             // 512 x 2048
  unsigned short* Wvb = Wkb + (size_t)512 * 2048;              // 512 x 2048
  unsigned short* Wob = Wvb + (size_t)512 * 2048;              // 2048 x 2048

  static bool attr_set = false;
  if (!attr_set) {
    hipFuncSetAttribute(reinterpret_cast<const void*>(qkv_gemm_kernel),
                        hipFuncAttributeMaxDynamicSharedMemorySize, 131072);
    hipFuncSetAttribute(reinterpret_cast<const void*>(oproj_gemm_kernel),
                        hipFuncAttributeMaxDynamicSharedMemorySize, 98304);
    attr_set = true;
  }

  cvt_all_kernel<<<9216, 256, 0, stream>>>(x, Wq, Wk, Wv, Wo, xb, Wqb, Wkb, Wvb, Wob);

  qkv_gemm_kernel<<<192, 512, 131072, stream>>>(xb, Wqb, Wkb, Wvb, Qb, Kb, Vtg);
  attn_kernel<<<dim3(8, 32, 2), 256, 0, stream>>>(Qb, Kb, Vtg, Ab);
  oproj_gemm_kernel<<<256, 512, 98304, stream>>>(Ab, Wob, out);
}

// Round 9
// 273.396 us; speedup vs baseline: 1.2197x; 1.2197x over previous
//
#include <hip/hip_runtime.h>
#include <stdint.h>

// Problem constants (fixed by the reference): B=2, S=2048, D=2048, Dh=64, Hq=32, Hkv=8, G=4.
#define S_LEN   2048
#define D_MODEL 2048
#define DKV     512

typedef __attribute__((ext_vector_type(8))) short short8;   // 8 x bf16
typedef __attribute__((ext_vector_type(4))) float f32x4;

__device__ static inline unsigned short f2bf(float f) {     // RNE float->bf16 (finite values)
  unsigned u = __builtin_bit_cast(unsigned, f);
  u += 0x7FFFu + ((u >> 16) & 1u);
  return (unsigned short)(u >> 16);
}
__device__ static inline float bf2f(unsigned short h) {
  return __builtin_bit_cast(float, ((unsigned)h) << 16);
}
// pack hi16(f0), hi16(f1) -> one dword (bf16 truncation; 1 v_perm_b32)
__device__ static inline unsigned packtrunc2(float f0, float f1) {
  return __builtin_amdgcn_perm(__builtin_bit_cast(unsigned, f1),
                               __builtin_bit_cast(unsigned, f0), 0x07060302u);
}

__device__ static inline void gload_lds16(const void* g, void* lds) {
  __builtin_amdgcn_global_load_lds((const __attribute__((address_space(1))) void*)g,
                                   (__attribute__((address_space(3))) void*)lds,
                                   16, 0, 0);
}

template <int N>
__device__ __forceinline__ void wait_vm() {
  if constexpr (N == 8)      asm volatile("s_waitcnt vmcnt(8)" ::: "memory");
  else if constexpr (N == 6) asm volatile("s_waitcnt vmcnt(6)" ::: "memory");
  else if constexpr (N == 4) asm volatile("s_waitcnt vmcnt(4)" ::: "memory");
  else if constexpr (N == 3) asm volatile("s_waitcnt vmcnt(3)" ::: "memory");
  else                       asm volatile("s_waitcnt vmcnt(0)" ::: "memory");
}

// fp32 -> bf16 bulk conversion for all 5 inputs + RoPE cos/sin table fill, ONE launch.
// Blocks 0..9215: conversions (exact region split, units of 8 floats).
// Blocks 9216..9471: tab[s*32+i] = (cos, sin)(s * 10000^(-i/32)), 2048x32 float2 (512KB).
__global__ __launch_bounds__(256) void cvt_all_kernel(
    const float* __restrict__ x, const float* __restrict__ wq, const float* __restrict__ wk,
    const float* __restrict__ wv, const float* __restrict__ wo,
    unsigned short* __restrict__ xb, unsigned short* __restrict__ wqb,
    unsigned short* __restrict__ wkb, unsigned short* __restrict__ wvb,
    unsigned short* __restrict__ wob, float2* __restrict__ tab) {
  if (blockIdx.x >= 9216) {             // RoPE table fill (one-shot, same math as reference)
    const int idx = (blockIdx.x - 9216) * 256 + threadIdx.x;   // 0..65535
    const int s = idx >> 5, i = idx & 31;
    const float inv = exp2f(-0.41524101186091903f * (float)i); // 10000^(-2i/64)
    const float th  = (float)s * inv;
    tab[idx] = make_float2(cosf(th), sinf(th));
    return;
  }
  int i = blockIdx.x * 256 + threadIdx.x;          // 0 .. 2359296-1
  const float* s; unsigned short* d;
  if (i < 1048576)      { s = x;  d = xb;  }
  else if (i < 1572864) { s = wq; d = wqb; i -= 1048576; }
  else if (i < 1703936) { s = wk; d = wkb; i -= 1572864; }
  else if (i < 1835008) { s = wv; d = wvb; i -= 1703936; }
  else                  { s = wo; d = wob; i -= 1835008; }
  const float4 a = ((const float4*)s)[i * 2];
  const float4 b = ((const float4*)s)[i * 2 + 1];
  unsigned short u[8] = {f2bf(a.x), f2bf(a.y), f2bf(a.z), f2bf(a.w),
                         f2bf(b.x), f2bf(b.y), f2bf(b.z), f2bf(b.w)};
  *(uint4*)(d + (size_t)i * 8) = *(const uint4*)u;
}

// ---------------------------------------------------------------------------------------------
// Deep-pipelined GEMM: C(M,N) = A(M,K=2048) @ B(N,K)^T, bf16 inputs.  (R1 structure)
// RMODE 0: plain. RMODE 1: fused RoPE via cos/sin TABLE on the fp32 accumulator (K).
// RMODE 2: fused RoPE + 0.1803 log2-softmax Q scale.
//   Pair-exchange algebra verified in R8 (passed): partner of element col is in lane lcol^1
//   of the same row -> __shfl_xor(v,1); even: v*c - p*s, odd: p*s... (see select below).
//   R8's on-device sinf/cosf (large-arg slow path, 192 low-occ blocks) cost qkv +46us ->
//   replaced by one 8B L2-cached table load per element (table 512KB, fits per-XCD L2).
// ---------------------------------------------------------------------------------------------
template <int BM, int CMODE, int RMODE, typename CT>
__device__ __forceinline__ void gemm_deep_body(
    const unsigned short* __restrict__ A, int lda,
    const unsigned short* __restrict__ B, int ldb,
    CT* __restrict__ C, int ldc, int m0, int n0, unsigned short* ldsu,
    const float2* __restrict__ tab) {
  constexpr int MI = BM / 32;             // 8 (BM=256) or 4 (BM=128)
  constexpr int NI = 4;
  constexpr int A_BYTES = BM * 64;        // BM*32*2B : 16KB or 8KB
  constexpr int B_BYTES = 256 * 64;       // 16KB
  constexpr int TILE_BYTES = A_BYTES + B_BYTES;
  constexpr int AL = BM / 128;            // A stage-loads per thread per phase: 2 or 1
  constexpr int LOADS = AL + 2;           // total stage-loads/thread/phase: 4 or 3
  constexpr int VMS = 2 * LOADS;          // steady-state vmcnt (retire 3-phases-old tile)

  const int tid  = threadIdx.x;
  const int lane = tid & 63;
  const int w    = tid >> 6;              // 0..7
  const int wm   = w >> 2;                // 0..1  (M halves)
  const int wn   = w & 3;                 // 0..3  (N quarters)
  const int lcol = lane & 15;
  const int lq   = lane >> 4;
  char* const ldsb = (char*)ldsu;

  // ---- staging lane constants (inverse swizzle on the global side) ----
  const int sl   = (lane & 7) ^ (lane >> 3);   // logical slab this lane must fetch
  const int colg = (sl & 3) * 8;               // element col within the 32-wide K-tile
  const unsigned short* gA[AL];
  const unsigned short* gB[2];
#pragma unroll
  for (int L = 0; L < AL; ++L) {
    const int r = 2 * (L * 64 + w * 8 + (lane >> 3)) + (sl >> 2);
    gA[L] = A + (size_t)(m0 + r) * lda + colg;
  }
#pragma unroll
  for (int L = 0; L < 2; ++L) {
    const int r = 2 * (L * 64 + w * 8 + (lane >> 3)) + (sl >> 2);
    gB[L] = B + (size_t)(n0 + r) * ldb + colg;
  }

  auto stage = [&](int tt) {
    char* const sb = ldsb + (tt & 3) * TILE_BYTES;
#pragma unroll
    for (int L = 0; L < AL; ++L)
      gload_lds16(gA[L] + tt * 32, sb + L * 8192 + w * 1024);
#pragma unroll
    for (int L = 0; L < 2; ++L)
      gload_lds16(gB[L] + tt * 32, sb + A_BYTES + L * 8192 + w * 1024);
  };

  // ---- fragment-read lane constant (swizzled) ----
  const int sR    = (((lcol & 1) << 2) | lq) ^ ((lcol >> 1) & 7);
  const int rdoff = (lcol >> 1) * 128 + sR * 16;

  f32x4 acc[MI][NI] = {};

  auto compute_tile = [&](char* buf) {
    short8 af[MI], bfr[NI];
#pragma unroll
    for (int mi = 0; mi < MI; ++mi)
      af[mi] = *(const short8*)(buf + wm * (MI * 1024) + mi * 1024 + rdoff);
#pragma unroll
    for (int ni = 0; ni < NI; ++ni)
      bfr[ni] = *(const short8*)(buf + A_BYTES + wn * 4096 + ni * 1024 + rdoff);
    __builtin_amdgcn_s_setprio(1);
#pragma unroll
    for (int mi = 0; mi < MI; ++mi)
#pragma unroll
      for (int ni = 0; ni < NI; ++ni)
        acc[mi][ni] = __builtin_amdgcn_mfma_f32_16x16x32_bf16(af[mi], bfr[ni], acc[mi][ni], 0, 0, 0);
    __builtin_amdgcn_s_setprio(0);
  };

  // prologue: 3 tiles in flight
  stage(0); stage(1); stage(2);

#define GPHASE(T, VMW, DOSTG)                          \
  do {                                                 \
    wait_vm<VMW>();                                    \
    __builtin_amdgcn_s_barrier();                      \
    asm volatile("" ::: "memory");                     \
    __builtin_amdgcn_sched_barrier(0);                 \
    if (DOSTG) stage((T) + 3);                         \
    compute_tile(ldsb + ((T) & 3) * TILE_BYTES);       \
  } while (0)

  for (int t4 = 0; t4 < 15; ++t4) {
    const int t = t4 * 4;
    GPHASE(t + 0, VMS, true);
    GPHASE(t + 1, VMS, true);
    GPHASE(t + 2, VMS, true);
    GPHASE(t + 3, VMS, true);
  }
  GPHASE(60, VMS,   true);
  GPHASE(61, VMS,   false);
  GPHASE(62, LOADS, false);
  GPHASE(63, 0,     false);
#undef GPHASE

  // epilogue (m97-verified C/D mapping; optional table-based fused RoPE)
#pragma unroll
  for (int mi = 0; mi < MI; ++mi)
#pragma unroll
    for (int ni = 0; ni < NI; ++ni)
#pragma unroll
      for (int r = 0; r < 4; ++r) {
        const int row = m0 + wm * (MI * 16) + mi * 16 + lq * 4 + r;
        const int col = n0 + wn * 64 + ni * 16 + lcol;
        float v = acc[mi][ni][r];
        if constexpr (RMODE > 0) {
          const float p = __shfl_xor(v, 1);           // partner element of the (even,odd) pair
          const int d = col & 63;
          const float2 cs = tab[(row & (S_LEN - 1)) * 32 + (d >> 1)];
          v = (d & 1) ? (p * cs.y + v * cs.x) : (v * cs.x - p * cs.y);
          if constexpr (RMODE == 2) v *= 0.1803368801111244f;  // 1/sqrt(64)*log2(e)
        }
        if constexpr (CMODE == 1) {
          // V pre-transpose: row = b*2048+s, col = d(0..511) -> Vt[(b*512+d)*2048 + s]
          C[((size_t)((row >> 11) * 512 + col)) * 2048 + (row & 2047)] = f2bf(v);
        } else if constexpr (CMODE == 2) {
          C[(size_t)row * ldc + col] = v;
        } else {
          C[(size_t)row * ldc + col] = f2bf(v);
        }
      }
}

// Fused QKV projection + table-RoPE: 192 blocks (16 M x [8 Q + 2 K + 2 V]), 512 thr, 128KB LDS.
__global__ __launch_bounds__(512, 2) void qkv_gemm_kernel(
    const unsigned short* __restrict__ x,
    const unsigned short* __restrict__ Wq, const unsigned short* __restrict__ Wk,
    const unsigned short* __restrict__ Wv,
    unsigned short* __restrict__ Qo, unsigned short* __restrict__ Ko,
    unsigned short* __restrict__ Vt, const float2* __restrict__ tab) {
  extern __shared__ __align__(16) unsigned short lds[];
  const int bid = blockIdx.x;                   // 192 = 8 XCDs * 24
  const int swz = (bid & 7) * 24 + (bid >> 3);  // bijective XCD swizzle (192 % 8 == 0)
  const int mt = swz / 12, nt = swz % 12;
  const int m0 = mt * 256;
  if (nt < 8)
    gemm_deep_body<256, 0, 2, unsigned short>(x, D_MODEL, Wq, D_MODEL, Qo, D_MODEL, m0, nt * 256, lds, tab);
  else if (nt < 10)
    gemm_deep_body<256, 0, 1, unsigned short>(x, D_MODEL, Wk, D_MODEL, Ko, DKV, m0, (nt - 8) * 256, lds, tab);
  else
    gemm_deep_body<256, 1, 0, unsigned short>(x, D_MODEL, Wv, D_MODEL, Vt, DKV, m0, (nt - 10) * 256, lds, tab);
}

// O-projection: bf16 A (attn out) x bf16 Wo -> fp32 out. 256 blocks (32 x 8) = exact CU fill.
__global__ __launch_bounds__(512, 2) void oproj_gemm_kernel(
    const unsigned short* __restrict__ A, const unsigned short* __restrict__ Wo,
    float* __restrict__ C) {
  extern __shared__ __align__(16) unsigned short lds[];
  const int bid = blockIdx.x;                   // 256 = 8 XCDs * 32
  const int swz = (bid & 7) * 32 + (bid >> 3);
  const int mt = swz >> 3, nt = swz & 7;
  gemm_deep_body<128, 2, 0, float>(A, D_MODEL, Wo, D_MODEL, C, D_MODEL, mt * 128, nt * 256, lds,
                                   (const float2*)nullptr);
}

// ---------------------------------------------------------------------------------------------
// Flash attention — EXACT session-best kernel (R0 original, 77.9 us measured):
// transposed scores (S^T = K@Q^T), non-rescaled log2-domain softmax, FOUR q-tiles per block
// {X,15-X,16+X,31-X} sharing every K/V LDS read (66 updates/block uniform, avg 2.32 tiles per
// kf/vf b128 read); P^T through LDS (Ps); l in VALU regs reduced by 2 shuffles.
// Grid (8, 32, 2); 2 blocks/CU (55KB LDS), 112 VGPR.
// ---------------------------------------------------------------------------------------------
__global__ __launch_bounds__(256, 2) void attn_kernel(const unsigned short* __restrict__ Q,
                                                      const unsigned short* __restrict__ K,
                                                      const unsigned short* __restrict__ Vt,
                                                      unsigned short* __restrict__ O) {
  const int hq = blockIdx.y;
  const int bb = blockIdx.z;
  const int hk = hq >> 2;
  const int tid  = threadIdx.x;
  const int lane = tid & 63;
  const int w    = tid >> 6;
  const int lcol = lane & 15;
  const int lq   = lane >> 4;
  const int trow = tid >> 2;            // staging row 0..63 (wave-private: w*16..w*16+15)
  const int tq   = (tid & 3) * 16;      // staging col quarter (16 elems = 32B)

  const int X = blockIdx.x;             // 0..7
  const int qt[4] = {X, 15 - X, 16 + X, 31 - X};   // ascending; total updates = 66

  // 72-elem rows (144B): 16B-aligned, non-pow2 bank stride. Ps[j] = Q tile j staging, then P^T.
  __shared__ unsigned short Ks[64 * 72];
  __shared__ unsigned short Vts[64 * 72];
  __shared__ unsigned short Ps[4][64 * 72];

  const int prow = w * 16 + lcol;

  // prefetch K/V tile 0 into registers
  uint4 kp0, kp1, vp0, vp1;
  {
    const unsigned short* gk = K + ((size_t)(bb * S_LEN + trow)) * DKV + hk * 64 + tq;
    kp0 = *(const uint4*)gk; kp1 = *(const uint4*)(gk + 8);
    const unsigned short* gv = Vt + ((size_t)(bb * DKV + hk * 64 + trow)) * S_LEN + tq;
    vp0 = *(const uint4*)gv; vp1 = *(const uint4*)(gv + 8);
  }

  // stage all 4 Q tiles (wave-private rows -> lgkm drain only, no barrier)
#pragma unroll
  for (int j = 0; j < 4; ++j) {
    const unsigned short* g = Q + ((size_t)(bb * S_LEN + qt[j] * 64 + trow)) * D_MODEL + hq * 64 + tq;
    *(uint4*)&Ps[j][trow * 72 + tq]     = *(const uint4*)g;
    *(uint4*)&Ps[j][trow * 72 + tq + 8] = *(const uint4*)(g + 8);
  }
  asm volatile("s_waitcnt lgkmcnt(0)" ::: "memory");

  short8 qf[4][2];                      // B-frags: n = q-row (w*16+lcol), k = d slab
#pragma unroll
  for (int j = 0; j < 4; ++j)
#pragma unroll
    for (int ks = 0; ks < 2; ++ks)
      qf[j][ks] = *(const short8*)&Ps[j][prow * 72 + ks * 32 + lq * 8];

  f32x4 Oacc[4][4] = {};                // [tile][dt]; O^T: col = q-row, row = d
  float lacc[4] = {0.f, 0.f, 0.f, 0.f}; // lq-partial row sums (reduced in epilogue)

  const int tmax = qt[3];
  for (int t = 0; t <= tmax; ++t) {
    __syncthreads();                    // all waves done reading Ks/Vts of iter t-1
    *(uint4*)&Ks[trow * 72 + tq]      = kp0;
    *(uint4*)&Ks[trow * 72 + tq + 8]  = kp1;
    *(uint4*)&Vts[trow * 72 + tq]     = vp0;
    *(uint4*)&Vts[trow * 72 + tq + 8] = vp1;
    if (t < tmax) {                     // prefetch next tile
      const int t1 = (t + 1) * 64;
      const unsigned short* gk = K + ((size_t)(bb * S_LEN + t1 + trow)) * DKV + hk * 64 + tq;
      kp0 = *(const uint4*)gk; kp1 = *(const uint4*)(gk + 8);
      const unsigned short* gv = Vt + ((size_t)(bb * DKV + hk * 64 + trow)) * S_LEN + t1 + tq;
      vp0 = *(const uint4*)gv; vp1 = *(const uint4*)(gv + 8);
    }
    __syncthreads();

    bool act[4];
#pragma unroll
    for (int j = 0; j < 4; ++j) act[j] = (t <= qt[j]);

    // ---- S phase: each kf b128 read feeds all active tiles' MFMAs ----
    f32x4 S[4][4] = {};                 // [tile][nt]
#pragma unroll
    for (int ks = 0; ks < 2; ++ks)
#pragma unroll
      for (int nt = 0; nt < 4; ++nt) {
        const short8 kf = *(const short8*)&Ks[(nt * 16 + lcol) * 72 + ks * 32 + lq * 8];
#pragma unroll
        for (int j = 0; j < 4; ++j)
          if (act[j])
            S[j][nt] = __builtin_amdgcn_mfma_f32_16x16x32_bf16(kf, qf[j][ks], S[j][nt], 0, 0, 0);
      }

    // ---- mask diagonal, p = exp2(S), accumulate l, pack P^T to LDS ----
#pragma unroll
    for (int j = 0; j < 4; ++j) {
      if (!act[j]) continue;
      if (t == qt[j]) {                 // diagonal tile for j
        const int qrow = qt[j] * 64 + prow;
#pragma unroll
        for (int nt = 0; nt < 4; ++nt)
#pragma unroll
          for (int r = 0; r < 4; ++r) {
            const int key = t * 64 + nt * 16 + lq * 4 + r;
            if (key > qrow) S[j][nt][r] = -1e30f;   // exp2 -> 0
          }
      }
#pragma unroll
      for (int nt = 0; nt < 4; ++nt) {
        const float p0 = __builtin_amdgcn_exp2f(S[j][nt][0]);
        const float p1 = __builtin_amdgcn_exp2f(S[j][nt][1]);
        const float p2 = __builtin_amdgcn_exp2f(S[j][nt][2]);
        const float p3 = __builtin_amdgcn_exp2f(S[j][nt][3]);
        lacc[j] += (p0 + p1) + (p2 + p3);
        unsigned u2[2] = {packtrunc2(p0, p1), packtrunc2(p2, p3)};
        *(uint2*)&Ps[j][prow * 72 + nt * 16 + lq * 4] = *(const uint2*)u2;
      }
    }
    asm volatile("s_waitcnt lgkmcnt(0)" ::: "memory");  // per-wave P write->read ordering

    // ---- O phase: each vf b128 read feeds all active tiles' MFMAs ----
#pragma unroll
    for (int ks = 0; ks < 2; ++ks) {
      short8 pf[4];
#pragma unroll
      for (int j = 0; j < 4; ++j)
        if (act[j]) pf[j] = *(const short8*)&Ps[j][prow * 72 + ks * 32 + lq * 8];
#pragma unroll
      for (int dt = 0; dt < 4; ++dt) {
        const short8 vf = *(const short8*)&Vts[(dt * 16 + lcol) * 72 + ks * 32 + lq * 8];
#pragma unroll
        for (int j = 0; j < 4; ++j)
          if (act[j])
            Oacc[j][dt] = __builtin_amdgcn_mfma_f32_16x16x32_bf16(vf, pf[j], Oacc[j][dt], 0, 0, 0);
      }
    }
  }

  // epilogue: reduce l across lq (2 shuffles per tile), normalize, store
#pragma unroll
  for (int j = 0; j < 4; ++j) {
    float l = lacc[j];
    l += __shfl_xor(l, 16);
    l += __shfl_xor(l, 32);
    const float inv = 1.0f / l;
    const int qrow = qt[j] * 64 + prow;
#pragma unroll
    for (int dt = 0; dt < 4; ++dt) {
      unsigned short u[4] = {f2bf(Oacc[j][dt][0] * inv), f2bf(Oacc[j][dt][1] * inv),
                             f2bf(Oacc[j][dt][2] * inv), f2bf(Oacc[j][dt][3] * inv)};
      *(uint2*)&O[(size_t)(bb * S_LEN + qrow) * D_MODEL + hq * 64 + dt * 16 + lq * 4] =
          *(const uint2*)u;
    }
  }
}

extern "C" void kernel_launch(void* const* d_in, const int* in_sizes, int n_in,
                              void* d_out, int out_size, void* d_ws, size_t ws_size,
                              hipStream_t stream) {
  const float* x  = (const float*)d_in[0];   // fp32 inputs per the reference dtypes
  const float* Wq = (const float*)d_in[1];
  const float* Wk = (const float*)d_in[2];
  const float* Wv = (const float*)d_in[3];
  const float* Wo = (const float*)d_in[4];
  float* out = (float*)d_out;                // fp32 output per the reference

  // Workspace (bf16 elements), total ~76 MiB + 512KB rope table:
  unsigned short* Qb  = (unsigned short*)d_ws;                 // 4096 x 2048
  unsigned short* Kb  = Qb  + (size_t)4096 * 2048;             // 4096 x 512
  unsigned short* Vtg = Kb  + (size_t)4096 * 512;              // 1024 x 2048 (V pre-transposed)
  unsigned short* Ab  = Vtg + (size_t)1024 * 2048;             // 4096 x 2048
  unsigned short* xb  = Ab  + (size_t)4096 * 2048;             // 4096 x 2048
  unsigned short* Wqb = xb  + (size_t)4096 * 2048;             // 2048 x 2048
  unsigned short* Wkb = Wqb + (size_t)2048 * 2048;             // 512 x 2048
  unsigned short* Wvb = Wkb + (size_t)512 * 2048;              // 512 x 2048
  unsigned short* Wob = Wvb + (size_t)512 * 2048;              // 2048 x 2048
  float2* tab = (float2*)(Wob + (size_t)2048 * 2048);          // 2048 x 32 float2 (512KB)

  static bool attr_set = false;
  if (!attr_set) {
    hipFuncSetAttribute(reinterpret_cast<const void*>(qkv_gemm_kernel),
                        hipFuncAttributeMaxDynamicSharedMemorySize, 131072);
    hipFuncSetAttribute(reinterpret_cast<const void*>(oproj_gemm_kernel),
                        hipFuncAttributeMaxDynamicSharedMemorySize, 98304);
    attr_set = true;
  }

  cvt_all_kernel<<<9472, 256, 0, stream>>>(x, Wq, Wk, Wv, Wo, xb, Wqb, Wkb, Wvb, Wob, tab);

  qkv_gemm_kernel<<<192, 512, 131072, stream>>>(xb, Wqb, Wkb, Wvb, Qb, Kb, Vtg, tab);
  attn_kernel<<<dim3(8, 32, 2), 256, 0, stream>>>(Qb, Kb, Vtg, Ab);
  oproj_gemm_kernel<<<256, 512, 98304, stream>>>(Ab, Wob, out);
}